// Round 1
// baseline (464.366 us; speedup 1.0000x reference)
//
#include <hip/hip_runtime.h>
#include <math.h>

#define LL 2048
#define MM 64
#define EE 64
#define HH 8
#define BB 16

// ws layout in floats:
//   Wc  [64][2048]            at 0
//   Ws  [64][2048]            at 131072
//   QF  [B][H][2][64m][64e]   at 262144           (4 MB)
//   KF  [B][H][2][64m][64e]   at 262144+1048576
//   Y   [B][H][2][64m][64e]   at 262144+2097152   (scaled, sign-folded)
#define WC_OFF 0
#define WS_OFF 131072
#define QF_OFF 262144
#define KF_OFF (262144 + 1048576)
#define Y_OFF  (262144 + 2097152)

__global__ __launch_bounds__(256) void basis_kernel(float* __restrict__ w) {
    int idx = blockIdx.x * 256 + threadIdx.x;      // 64*2048 total
    int m = idx >> 11, t = idx & 2047;
    int j = (m * t) & 2047;
    float ang = (float)j * 0.0030679615757712823f; // 2*pi/2048
    float s, c;
    sincosf(ang, &s, &c);
    w[WC_OFF + idx] = c;
    w[WS_OFF + idx] = s;
}

// Forward truncated DFT: X[m][e] = sum_t A[t][e] * exp(-2pi i m t / L)
// block: (e-group of 8, b, tensor(q/k)); 512 threads = 8 waves (wave -> 8 modes)
__global__ __launch_bounds__(512) void fdft_kernel(const float* __restrict__ q,
                                                   const float* __restrict__ k,
                                                   float* __restrict__ ws) {
    const int eg = blockIdx.x;   // 0..7
    const int b  = blockIdx.y;   // 0..15
    const int tz = blockIdx.z;   // 0: q, 1: k
    const float* __restrict__ src = tz ? k : q;
    float* __restrict__ dst = ws + (tz ? KF_OFF : QF_OFF);
    const float* __restrict__ wc  = ws + WC_OFF;
    const float* __restrict__ wsn = ws + WS_OFF;

    __shared__ float tileA[64][64];   // [t][j], j = (e-e0)*8 + h  (contiguous in src)

    const int tid  = threadIdx.x;
    const int lane = tid & 63;
    const int wid  = tid >> 6;
    const int mbase = __builtin_amdgcn_readfirstlane(wid) * 8;  // keep scalar -> s_load basis

    float accr[8], acci[8];
#pragma unroll
    for (int i = 0; i < 8; ++i) { accr[i] = 0.f; acci[i] = 0.f; }

    const long srcbase = (long)b * LL * 512 + eg * 64;  // + t*512 + j

    for (int t0 = 0; t0 < LL; t0 += 64) {
        __syncthreads();
#pragma unroll
        for (int it = 0; it < 2; ++it) {            // 1024 float4s / 512 threads
            int i = tid + it * 512;
            int t = i >> 4, c4 = i & 15;
            const float4 v = *(const float4*)(src + srcbase + (long)(t0 + t) * 512 + c4 * 4);
            *(float4*)(&tileA[t][c4 * 4]) = v;
        }
        __syncthreads();
        for (int tt4 = 0; tt4 < 16; ++tt4) {
            float a0 = tileA[tt4 * 4 + 0][lane];
            float a1 = tileA[tt4 * 4 + 1][lane];
            float a2 = tileA[tt4 * 4 + 2][lane];
            float a3 = tileA[tt4 * 4 + 3][lane];
#pragma unroll
            for (int i = 0; i < 8; ++i) {
                const float4 c4v = *(const float4*)(wc  + (mbase + i) * 2048 + t0 + tt4 * 4);
                const float4 s4v = *(const float4*)(wsn + (mbase + i) * 2048 + t0 + tt4 * 4);
                accr[i] += a0 * c4v.x; accr[i] += a1 * c4v.y;
                accr[i] += a2 * c4v.z; accr[i] += a3 * c4v.w;
                acci[i] -= a0 * s4v.x; acci[i] -= a1 * s4v.y;
                acci[i] -= a2 * s4v.z; acci[i] -= a3 * s4v.w;
            }
        }
    }
    // write [b][h][p][m][e]
    const int h = lane & 7;
    const int e = eg * 8 + (lane >> 3);
    float* outp = dst + ((b * 8 + h) * 2) * 4096 + e;
#pragma unroll
    for (int i = 0; i < 8; ++i) {
        outp[(mbase + i) * 64]        = accr[i];
        outp[4096 + (mbase + i) * 64] = acci[i];
    }
}

// Middle: S = Q^T K (complex, contract e), tanh(re/im), xqkv = K * T^T, scale -> Y
// block per (h, b); 256 threads = 4 waves (wave -> 16 x-modes)
__global__ __launch_bounds__(256) void mid_kernel(float* __restrict__ ws) {
    const int h = blockIdx.x, b = blockIdx.y;
    const float* __restrict__ QF = ws + QF_OFF + ((b * 8 + h) * 2) * 4096;
    const float* __restrict__ KF = ws + KF_OFF + ((b * 8 + h) * 2) * 4096;
    float* __restrict__ Y = ws + Y_OFF + ((b * 8 + h) * 2) * 4096;

    __shared__ float Qs[2][64][64];   // Q [x][e]; reused as T [x][y] after step 3
    __shared__ float Ksw[2][64][64];  // K [m][e] stored XOR-swizzled: [m][e^m]

    const int tid = threadIdx.x;
    for (int i = tid; i < 4096; i += 256) {
        int m = i >> 6, e = i & 63;
        Qs[0][m][e] = QF[i];
        Qs[1][m][e] = QF[4096 + i];
        Ksw[0][m][e ^ m] = KF[i];
        Ksw[1][m][e ^ m] = KF[4096 + i];
    }
    __syncthreads();

    const int lane = tid & 63;
    const int wid  = tid >> 6;   // 0..3
    const int xb   = wid * 16;

    // step 3: S[x][y], y = lane
    float sr[16], si[16];
#pragma unroll
    for (int i = 0; i < 16; ++i) { sr[i] = 0.f; si[i] = 0.f; }
    const int y = lane;
    for (int e = 0; e < 64; ++e) {
        float kr = Ksw[0][y][e ^ y];
        float ki = Ksw[1][y][e ^ y];
#pragma unroll
        for (int i = 0; i < 16; ++i) {
            float qr = Qs[0][xb + i][e];
            float qi = Qs[1][xb + i][e];
            sr[i] += qr * kr; sr[i] -= qi * ki;
            si[i] += qr * ki; si[i] += qi * kr;
        }
    }
    float tr[16], ti[16];
#pragma unroll
    for (int i = 0; i < 16; ++i) { tr[i] = tanhf(sr[i]); ti[i] = tanhf(si[i]); }
    __syncthreads();   // done reading Q
#pragma unroll
    for (int i = 0; i < 16; ++i) {
        Qs[0][xb + i][y] = tr[i];   // T[x][y]
        Qs[1][xb + i][y] = ti[i];
    }
    __syncthreads();

    // step 4: xqkv[e][x] = sum_y T[x][y] * K[y][e-chan]  (e = lane)
    float vr[16], vi[16];
#pragma unroll
    for (int i = 0; i < 16; ++i) { vr[i] = 0.f; vi[i] = 0.f; }
    const int e = lane;
    for (int yy = 0; yy < 64; ++yy) {
        float kr = Ksw[0][yy][e ^ yy];
        float ki = Ksw[1][yy][e ^ yy];
#pragma unroll
        for (int i = 0; i < 16; ++i) {
            float trr = Qs[0][xb + i][yy];
            float tii = Qs[1][xb + i][yy];
            vr[i] += trr * kr; vr[i] -= tii * ki;
            vi[i] += trr * ki; vi[i] += tii * kr;
        }
    }
#pragma unroll
    for (int i = 0; i < 16; ++i) {
        int x = xb + i;
        float f = (x == 0 ? 1.0f : 2.0f) * (1.0f / (2048.0f * 4096.0f));
        Y[x * 64 + e]        =  f * vr[i];   // Yr
        Y[4096 + x * 64 + e] = -f * vi[i];   // Yi (sign folded: out = sum c*Yr + s*Yi)
    }
}

// Inverse: out[b][t][h][e] = sum_m Wc[m][t]*Yr[m][e] + Ws[m][t]*Yi[m][e]
// block: (t-chunk of 256, h, b); lane -> t, 64 e-accumulators
__global__ __launch_bounds__(256) void idft_kernel(const float* __restrict__ ws,
                                                   float* __restrict__ out) {
    const int tc = blockIdx.x;   // 0..7
    const int h  = blockIdx.y;   // 0..7
    const int b  = blockIdx.z;   // 0..15
    const int t  = tc * 256 + threadIdx.x;
    const float* __restrict__ wc  = ws + WC_OFF;
    const float* __restrict__ wsn = ws + WS_OFF;
    const float* __restrict__ yr  = ws + Y_OFF + ((b * 8 + h) * 2) * 4096;
    const float* __restrict__ yi  = yr + 4096;

    float acc[64];
#pragma unroll
    for (int e = 0; e < 64; ++e) acc[e] = 0.f;

    for (int m = 0; m < 64; ++m) {
        float c = wc[m * 2048 + t];     // coalesced 256B/wave, L2-resident
        float s = wsn[m * 2048 + t];
#pragma unroll
        for (int e = 0; e < 64; ++e) {  // Y rows are wave-uniform -> s_load
            acc[e] += yr[m * 64 + e] * c;
            acc[e] += yi[m * 64 + e] * s;
        }
    }
    float4* op = (float4*)(out + (((long)b * 2048 + t) * 8 + h) * 64);
#pragma unroll
    for (int e4 = 0; e4 < 16; ++e4)
        op[e4] = make_float4(acc[4 * e4], acc[4 * e4 + 1], acc[4 * e4 + 2], acc[4 * e4 + 3]);
}

extern "C" void kernel_launch(void* const* d_in, const int* in_sizes, int n_in,
                              void* d_out, int out_size, void* d_ws, size_t ws_size,
                              hipStream_t stream) {
    const float* q = (const float*)d_in[0];
    const float* k = (const float*)d_in[1];
    // d_in[2] (v) is unused by the reference.
    float* ws = (float*)d_ws;      // needs ~13 MB
    float* out = (float*)d_out;

    hipLaunchKernelGGL(basis_kernel, dim3(512), dim3(256), 0, stream, ws);
    hipLaunchKernelGGL(fdft_kernel, dim3(8, 16, 2), dim3(512), 0, stream, q, k, ws);
    hipLaunchKernelGGL(mid_kernel, dim3(8, 16), dim3(256), 0, stream, ws);
    hipLaunchKernelGGL(idft_kernel, dim3(8, 8, 16), dim3(256), 0, stream, ws, out);
}

// Round 2
// 167.444 us; speedup vs baseline: 2.7733x; 2.7733x over previous
//
#include <hip/hip_runtime.h>
#include <math.h>

// ws layout (float offsets):
//   cosTM [1024][64]  (fdft basis, [t][m], cos)         @ 0
//   sinTM [1024][64]  (fdft basis, [t][m], MINUS sin)   @ 65536
//   cosMT [64][1088]  (idft basis, [m][t], cos)         @ 131072
//   sinMT [64][1088]  (idft basis, [m][t], plus sin)    @ 200704
//   XP    [tz2][half2][b16][p2][m64][ch512]             @ 270336   (16 MB)
//   Y     [b16][p2][m64][ch512']  ch' = h*64+e          @ 4464640  (2 MB)
#define COSTM_OFF 0
#define SINTM_OFF 65536
#define COSMT_OFF 131072
#define SINMT_OFF 200704
#define XP_OFF    270336
#define Y_OFF     4464640

__global__ __launch_bounds__(256) void basis_kernel(float* __restrict__ w) {
    int idx = blockIdx.x * 256 + threadIdx.x;
    const float th = 0.0030679615757712823f; // 2*pi/2048
    if (idx < 65536) {
        int t = idx >> 6, m = idx & 63;
        int j = (m * t) & 2047;
        float s, c; sincosf(th * (float)j, &s, &c);
        w[COSTM_OFF + idx] = c;
        w[SINTM_OFF + idx] = -s;   // sign folded: Xi = sum v * (-sin)
    }
    if (idx < 69632) {
        int m = idx / 1088, t = idx - m * 1088;
        int j = (m * t) & 2047;
        float s, c; sincosf(th * (float)j, &s, &c);
        w[COSMT_OFF + idx] = c;
        w[SINMT_OFF + idx] = s;
    }
}

// Forward folded DFT. Xr[m] = a0 + (-1)^m a1024 + sum_{t=1}^{1023} u[t]cos(mt')
// Xi[m] = -sum v[t] sin(mt').  Loop t=0..1023 with u[0]=a0+a1024 (odd-m fixed
// in epilogue), v[0] irrelevant (sin=0).  Block: 64m x 64ch tile, one t-half.
__global__ __launch_bounds__(256) void fdft_kernel(const float* __restrict__ q,
                                                   const float* __restrict__ k,
                                                   float* __restrict__ ws) {
    const int ch0  = blockIdx.x * 64;
    const int b    = blockIdx.y;
    const int tz   = blockIdx.z >> 1;
    const int half = blockIdx.z & 1;
    const float* __restrict__ src   = tz ? k : q;
    const float* __restrict__ cosTM = ws + COSTM_OFF;
    const float* __restrict__ sinTM = ws + SINTM_OFF;
    float* __restrict__ xp = ws + XP_OFF + (size_t)((tz * 2 + half) * 16 + b) * 65536;

    __shared__ float uL[32][64], vL[32][64], cL[32][64], sL[32][64];

    const int tid = threadIdx.x;
    const int m0 = (tid & 15) * 4;   // 4 modes
    const int c0 = (tid >> 4) * 4;   // 4 channels (local)

    float ar[4][4] = {{0.f}}, ai[4][4] = {{0.f}};

    const long abase = (long)b * 2048 * 512 + ch0;
    const int tbeg = half * 512;

    for (int t0 = tbeg; t0 < tbeg + 512; t0 += 32) {
        __syncthreads();
#pragma unroll
        for (int s = 0; s < 2; ++s) {
            int slot = tid + s * 256;           // 512 slots = 32 rows x 16 f4
            int row = slot >> 4, c4 = slot & 15;
            int t = t0 + row;
            int pr = (t == 0) ? 1024 : (2048 - t);
            float4 av = *(const float4*)(src + abase + (long)t  * 512 + c4 * 4);
            float4 pv = *(const float4*)(src + abase + (long)pr * 512 + c4 * 4);
            *(float4*)(&uL[row][c4 * 4]) = make_float4(av.x + pv.x, av.y + pv.y, av.z + pv.z, av.w + pv.w);
            *(float4*)(&vL[row][c4 * 4]) = make_float4(av.x - pv.x, av.y - pv.y, av.z - pv.z, av.w - pv.w);
        }
#pragma unroll
        for (int s = 0; s < 2; ++s) {
            int slot = tid + s * 256;
            int row = slot >> 4, c4 = slot & 15;
            *(float4*)(&cL[row][c4 * 4]) = *(const float4*)(cosTM + (t0 + row) * 64 + c4 * 4);
            *(float4*)(&sL[row][c4 * 4]) = *(const float4*)(sinTM + (t0 + row) * 64 + c4 * 4);
        }
        __syncthreads();
        for (int tt = 0; tt < 32; ++tt) {
            float4 c4v = *(const float4*)(&cL[tt][m0]);
            float4 s4v = *(const float4*)(&sL[tt][m0]);
            float4 u4  = *(const float4*)(&uL[tt][c0]);
            float4 v4  = *(const float4*)(&vL[tt][c0]);
            const float cc[4] = {c4v.x, c4v.y, c4v.z, c4v.w};
            const float ss[4] = {s4v.x, s4v.y, s4v.z, s4v.w};
            const float uu[4] = {u4.x, u4.y, u4.z, u4.w};
            const float vv[4] = {v4.x, v4.y, v4.z, v4.w};
#pragma unroll
            for (int im = 0; im < 4; ++im)
#pragma unroll
                for (int ic = 0; ic < 4; ++ic) {
                    ar[im][ic] += cc[im] * uu[ic];
                    ai[im][ic] += ss[im] * vv[ic];
                }
        }
    }
    if (half == 0) {   // odd-m correction: u[0] included a1024 with +1 for all m
        float4 a1024 = *(const float4*)(src + abase + 1024L * 512 + c0);
        const float aa[4] = {a1024.x, a1024.y, a1024.z, a1024.w};
#pragma unroll
        for (int ic = 0; ic < 4; ++ic) {
            ar[1][ic] -= 2.f * aa[ic];
            ar[3][ic] -= 2.f * aa[ic];
        }
    }
#pragma unroll
    for (int im = 0; im < 4; ++im) {
        float* pr = xp + (m0 + im) * 512 + ch0 + c0;
        *(float4*)pr           = make_float4(ar[im][0], ar[im][1], ar[im][2], ar[im][3]);
        *(float4*)(pr + 32768) = make_float4(ai[im][0], ai[im][1], ai[im][2], ai[im][3]);
    }
}

// Middle: per (b,h). S = Q K^H-free complex einsum, tanh re/im, xqkv, scale.
__global__ __launch_bounds__(256) void mid_kernel(float* __restrict__ ws) {
    const int h = blockIdx.x, b = blockIdx.y;
    const float* __restrict__ Xq0 = ws + XP_OFF + (size_t)(0 * 16 + b) * 65536;
    const float* __restrict__ Xq1 = ws + XP_OFF + (size_t)(1 * 16 + b) * 65536;
    const float* __restrict__ Xk0 = ws + XP_OFF + (size_t)(2 * 16 + b) * 65536;
    const float* __restrict__ Xk1 = ws + XP_OFF + (size_t)(3 * 16 + b) * 65536;
    float* __restrict__ Y = ws + Y_OFF + (size_t)b * 65536;

    __shared__ float Qs[2][64][64];   // Q [x][e]; reused as T [x][y]
    __shared__ float Ksw[2][64][64];  // K [m][e] XOR-swizzled [m][e^m]

    const int tid = threadIdx.x;
    for (int i = tid; i < 4096; i += 256) {
        int m = i >> 6, e = i & 63;
        int off = m * 512 + e * 8 + h;
        Qs[0][m][e]      = Xq0[off] + Xq1[off];
        Qs[1][m][e]      = Xq0[32768 + off] + Xq1[32768 + off];
        Ksw[0][m][e ^ m] = Xk0[off] + Xk1[off];
        Ksw[1][m][e ^ m] = Xk0[32768 + off] + Xk1[32768 + off];
    }
    __syncthreads();

    const int lane = tid & 63;
    const int wid  = tid >> 6;
    const int xb   = wid * 16;

    float sr[16], si[16];
#pragma unroll
    for (int i = 0; i < 16; ++i) { sr[i] = 0.f; si[i] = 0.f; }
    const int y = lane;
    for (int e = 0; e < 64; ++e) {
        float kr = Ksw[0][y][e ^ y];
        float ki = Ksw[1][y][e ^ y];
#pragma unroll
        for (int i = 0; i < 16; ++i) {
            float qr = Qs[0][xb + i][e];
            float qi = Qs[1][xb + i][e];
            sr[i] += qr * kr; sr[i] -= qi * ki;
            si[i] += qr * ki; si[i] += qi * kr;
        }
    }
    float tr[16], ti[16];
#pragma unroll
    for (int i = 0; i < 16; ++i) { tr[i] = tanhf(sr[i]); ti[i] = tanhf(si[i]); }
    __syncthreads();
#pragma unroll
    for (int i = 0; i < 16; ++i) {
        Qs[0][xb + i][y] = tr[i];
        Qs[1][xb + i][y] = ti[i];
    }
    __syncthreads();

    float vr[16], vi[16];
#pragma unroll
    for (int i = 0; i < 16; ++i) { vr[i] = 0.f; vi[i] = 0.f; }
    const int e = lane;
    for (int yy = 0; yy < 64; ++yy) {
        float kr = Ksw[0][yy][e ^ yy];
        float ki = Ksw[1][yy][e ^ yy];
#pragma unroll
        for (int i = 0; i < 16; ++i) {
            float trr = Qs[0][xb + i][yy];
            float tii = Qs[1][xb + i][yy];
            vr[i] += trr * kr; vr[i] -= tii * ki;
            vi[i] += trr * ki; vi[i] += tii * kr;
        }
    }
#pragma unroll
    for (int i = 0; i < 16; ++i) {
        int x = xb + i;
        float f = (x == 0 ? 1.0f : 2.0f) * (1.0f / (2048.0f * 4096.0f));
        Y[x * 512 + h * 64 + e]         =  f * vr[i];  // Yr
        Y[32768 + x * 512 + h * 64 + e] = -f * vi[i];  // Yi (sign folded)
    }
}

// Inverse folded DFT: P[t]=sum cos*Yr, Q[t]=sum sin*Yi;
// out[t]=P+Q (t<=1024), out[2048-t]=P-Q (1<=t<=1023).
__global__ __launch_bounds__(256) void idft_kernel(const float* __restrict__ ws,
                                                   float* __restrict__ out) {
    const int tt0 = blockIdx.x * 64;   // 0..16 tiles (t<=1024 masked)
    const int ch0 = blockIdx.y * 64;
    const int b   = blockIdx.z;
    const float* __restrict__ cosMT = ws + COSMT_OFF;
    const float* __restrict__ sinMT = ws + SINMT_OFF;
    const float* __restrict__ Y = ws + Y_OFF + (size_t)b * 65536;

    __shared__ float bas[2][64][64];   // [cos/sin][m][tloc]
    __shared__ float Ys[2][64][64];    // [p][m][chloc]

    const int tid = threadIdx.x;
#pragma unroll
    for (int s = 0; s < 8; ++s) {
        int slot = tid + s * 256;      // 2048 f4 slots
        int tab = slot >> 10, m = (slot >> 4) & 63, c4 = slot & 15;
        const float* bsrc = tab ? sinMT : cosMT;
        *(float4*)(&bas[tab][m][c4 * 4]) = *(const float4*)(bsrc + m * 1088 + tt0 + c4 * 4);
    }
#pragma unroll
    for (int s = 0; s < 8; ++s) {
        int slot = tid + s * 256;
        int p = slot >> 10, m = (slot >> 4) & 63, c4 = slot & 15;
        *(float4*)(&Ys[p][m][c4 * 4]) = *(const float4*)(Y + (p * 64 + m) * 512 + ch0 + c4 * 4);
    }
    __syncthreads();

    const int tL = (tid & 15) * 4;
    const int cL = (tid >> 4) * 4;
    float P[4][4] = {{0.f}}, Qa[4][4] = {{0.f}};
    for (int m = 0; m < 64; ++m) {
        float4 c4v = *(const float4*)(&bas[0][m][tL]);
        float4 s4v = *(const float4*)(&bas[1][m][tL]);
        float4 yr4 = *(const float4*)(&Ys[0][m][cL]);
        float4 yi4 = *(const float4*)(&Ys[1][m][cL]);
        const float cc[4] = {c4v.x, c4v.y, c4v.z, c4v.w};
        const float ss[4] = {s4v.x, s4v.y, s4v.z, s4v.w};
        const float rr[4] = {yr4.x, yr4.y, yr4.z, yr4.w};
        const float ii[4] = {yi4.x, yi4.y, yi4.z, yi4.w};
#pragma unroll
        for (int it = 0; it < 4; ++it)
#pragma unroll
            for (int ic = 0; ic < 4; ++ic) {
                P[it][ic]  += cc[it] * rr[ic];
                Qa[it][ic] += ss[it] * ii[ic];
            }
    }
#pragma unroll
    for (int it = 0; it < 4; ++it) {
        int t = tt0 + tL + it;
        if (t <= 1024) {
            float4 s0 = make_float4(P[it][0] + Qa[it][0], P[it][1] + Qa[it][1],
                                    P[it][2] + Qa[it][2], P[it][3] + Qa[it][3]);
            *(float4*)(out + ((long)b * 2048 + t) * 512 + ch0 + cL) = s0;
        }
        if (t >= 1 && t <= 1023) {
            float4 s1 = make_float4(P[it][0] - Qa[it][0], P[it][1] - Qa[it][1],
                                    P[it][2] - Qa[it][2], P[it][3] - Qa[it][3]);
            *(float4*)(out + ((long)b * 2048 + (2048 - t)) * 512 + ch0 + cL) = s1;
        }
    }
}

extern "C" void kernel_launch(void* const* d_in, const int* in_sizes, int n_in,
                              void* d_out, int out_size, void* d_ws, size_t ws_size,
                              hipStream_t stream) {
    const float* q = (const float*)d_in[0];
    const float* k = (const float*)d_in[1];
    float* ws = (float*)d_ws;      // ~21 MB used
    float* out = (float*)d_out;

    hipLaunchKernelGGL(basis_kernel, dim3(272), dim3(256), 0, stream, ws);
    hipLaunchKernelGGL(fdft_kernel, dim3(8, 16, 4), dim3(256), 0, stream, q, k, ws);
    hipLaunchKernelGGL(mid_kernel, dim3(8, 16), dim3(256), 0, stream, ws);
    hipLaunchKernelGGL(idft_kernel, dim3(17, 8, 16), dim3(256), 0, stream, ws, out);
}